// Round 8
// baseline (299.925 us; speedup 1.0000x reference)
//
#include <hip/hip_runtime.h>
#include <math.h>

#define LL 3136
#define HH 56
#define WW 56
#define DI 192
#define NB 2
#define NCOUT 38
#define NKO 152
#define NST 16
#define NDTR 6
#define NCH 98     // number of scan chunks (3136 = 98*32)
#define CLEN 32    // LL / NCH
#define THETA_C 0.6f

// padded A field: 58x58 pixels, K=384 (t*192+c) contiguous
#define HP 58
#define PIXP (HP*HP)          // 3364
#define KK 384
#define NPAD 160              // padded N for GEMM cols
#define AELEMS ((size_t)NB*PIXP*KK)       // 2,583,552 bf16 per array
#define BPELEMS (9*12*NPAD*32)            // 552,960 per (hi|lo)
#define BDELEMS (12*NPAD*32)              // 61,440 per (hi|lo)
#define PSZ ((size_t)NB*LL*NPAD)          // 1,003,520 floats per partial
#define AZTOT (2*NB*228*96)               // 87,552 border-zero slots
#define TOPWN (96*DI)                     // 18,432
#define SCANSZ ((size_t)NB*4*NCH*DI*NST)  // 2,408,448 floats per scan array

typedef short s8v __attribute__((ext_vector_type(8)));
typedef float f4v __attribute__((ext_vector_type(4)));

__device__ __forceinline__ float siluf(float x){ return x * (1.0f / (1.0f + __expf(-x))); }
__device__ __forceinline__ float softplusf(float x){ return (x > 20.0f) ? x : log1pf(__expf(x)); }
__device__ __forceinline__ void split_bf16(float v, unsigned short& hi, unsigned short& lo){
  unsigned bits = __float_as_uint(v);
  hi = (unsigned short)(bits >> 16);
  float hif = __uint_as_float(((unsigned)hi) << 16);
  float lof = v - hif;
  lo = (unsigned short)(__float_as_uint(lof) >> 16);
}

// ---------------- K1: in_proj GEMM ----------------
__global__ __launch_bounds__(512) void k_inproj(const float* __restrict__ x,
                                                const float* __restrict__ w,
                                                float* __restrict__ xz){
  __shared__ float xsh[16][100];
  int bl0 = blockIdx.x * 16;
  int tid = threadIdx.x;
  for (int i = tid; i < 16*96; i += 512){
    xsh[i/96][i%96] = x[(size_t)(bl0 + i/96)*96 + (i%96)];
  }
  __syncthreads();
  int lt = tid & 15, e0 = tid >> 4;
  int bl = bl0 + lt;
  int b = bl / LL, l = bl % LL;
  for (int j = 0; j < 12; ++j){
    int e = e0 + 32*j;
    const float* wr = w + e*96;
    float acc = 0.f;
    #pragma unroll
    for (int c = 0; c < 96; c += 4){
      acc += xsh[lt][c]*wr[c] + xsh[lt][c+1]*wr[c+1]
           + xsh[lt][c+2]*wr[c+2] + xsh[lt][c+3]*wr[c+3];
    }
    xz[((size_t)b*384 + e)*LL + l] = acc;
  }
}

// ---------------- K1b: transpose xt (NHWC -> [b][c][l]) ----------------
__global__ __launch_bounds__(256) void k_txt(const float* __restrict__ xt,
                                             float* __restrict__ xtT){
  __shared__ float tile[16][97];
  int l0 = blockIdx.x * 16; int b = blockIdx.y;
  for (int i = threadIdx.x; i < 16*96; i += 256){
    int ll = i / 96, c = i % 96;
    tile[ll][c] = xt[((size_t)b*LL + l0 + ll)*96 + c];
  }
  __syncthreads();
  for (int o = threadIdx.x; o < 96*16; o += 256){
    int c = o >> 4, ll = o & 15;
    xtT[((size_t)b*96 + c)*LL + l0 + ll] = tile[ll][c];
  }
}

// ---------------- K2: fused depthwise conv (xc) + grouped conv (xtc) ----------------
__global__ __launch_bounds__(256) void k_conv(const float* __restrict__ xz,
                                              const float* __restrict__ xtT,
                                              const float* __restrict__ c2w,
                                              const float* __restrict__ c2b,
                                              const float* __restrict__ cxw,
                                              const float* __restrict__ cxb,
                                              float* __restrict__ xc,
                                              float* __restrict__ xtc){
  const int n1 = NB*DI*LL;
  int idx = blockIdx.x*256 + threadIdx.x;
  if (idx >= 2*n1) return;
  int isXT = idx >= n1;
  int id = isXT ? idx - n1 : idx;
  int l = id % LL; int d = (id / LL) % DI; int b = id / (DI*LL);
  int h = l / WW, wp = l % WW;
  const float* src; const float* wk; float acc;
  if (!isXT){
    src = xz + ((size_t)b*384 + d)*LL;
    wk = c2w + d*9; acc = c2b[d];
  } else {
    src = xtT + ((size_t)b*96 + (d >> 1))*LL;
    wk = cxw + d*9; acc = cxb[d];
  }
  #pragma unroll
  for (int dh = 0; dh < 3; ++dh){
    int hh = h + dh - 1; if (hh < 0 || hh >= HH) continue;
    const float* row = src + hh*WW;
    #pragma unroll
    for (int dw = 0; dw < 3; ++dw){
      int wq = wp + dw - 1; if (wq < 0 || wq >= WW) continue;
      acc += wk[dh*3+dw] * row[wq];
    }
  }
  (isXT ? xtc : xc)[((size_t)b*DI + d)*LL + l] = siluf(acc);
}

// ---------------- K4: pools -> 2 directional base sequences ----------------
__global__ __launch_bounds__(256) void k_xs(const float* __restrict__ xc,
                                            const float* __restrict__ xtc,
                                            float* __restrict__ xs){
  __shared__ float T[4][32][57];
  int h = blockIdx.x, b = blockIdx.y, dt = blockIdx.z;
  int d0 = dt*32;
  int i0 = (h >> 1) * 2;
  const float* rsrc = (h & 1) ? xtc : xc;
  for (int i = threadIdx.x; i < 4*32*56; i += 256){
    int pl = i / (32*56); int r = i % (32*56); int dl = r / 56; int w = r % 56;
    const float* s; int row;
    if (pl == 0){ s = xc;  row = h; }
    else if (pl == 1){ s = xtc; row = h; }
    else if (pl == 2){ s = rsrc; row = i0; }
    else { s = rsrc; row = i0 + 1; }
    T[pl][dl][w] = s[((size_t)b*DI + d0 + dl)*LL + row*WW + w];
  }
  __syncthreads();
  for (int o = threadIdx.x; o < 2*56*32; o += 256){
    int out = o / (56*32); int r = o % (56*32); int wp = r / 32; int dl = r & 31;
    if (out == 1){
      int s = wp & 1; int w0 = (wp >> 1) * 2;
      float a0 = T[s][dl][w0], a1 = T[s][dl][w0+1];
      float ic = 0.5f*(a0+a1) + fmaxf(a0,a1);
      xs[(((size_t)b*2 + 1)*LL + h*WW + wp)*DI + d0 + dl] = ic;
    } else {
      float r0 = T[2][dl][wp], r1 = T[3][dl][wp];
      float ir = 0.5f*(r0+r1) + fmaxf(r0,r1);
      xs[(((size_t)b*2 + 0)*LL + wp*HH + h)*DI + d0 + dl] = ir;
    }
  }
}

// ---------------- K5a: kernel_diff ----------------
__global__ __launch_bounds__(256) void k_kd(const float* __restrict__ xpw, float* __restrict__ kd){
  int idx = blockIdx.x*256 + threadIdx.x;
  if (idx >= NKO*DI) return;
  const float* p = xpw + (size_t)idx*18;
  float s = 0.f;
  #pragma unroll
  for (int i = 0; i < 18; ++i) s += p[i];
  kd[idx] = s;
}

// ---------------- K5b: pack weights + A-border zero + opw transpose (fused ranges) ----------------
__global__ __launch_bounds__(256) void k_wpack(const float* __restrict__ xpw,
                                               const float* __restrict__ kd,
                                               const float* __restrict__ opw,
                                               unsigned short* __restrict__ Bp,
                                               unsigned short* __restrict__ Bd,
                                               unsigned short* __restrict__ Ah,
                                               unsigned short* __restrict__ Al,
                                               float* __restrict__ opwT){
  int idx = blockIdx.x*256 + threadIdx.x;
  if (idx < BPELEMS){
    int q = idx & 31; int n = (idx >> 5) % NPAD; int oks = idx / (NPAD*32);
    int ks = oks % 12, off = oks / 12;
    int k = ks*32 + q;
    int t = k / DI, c = k % DI;
    float v = 0.f;
    if (n < NKO){
      float w = xpw[((size_t)(n*DI + c)*2 + t)*9 + off];
      v = 2.f*w;
      if (off == 4) v -= THETA_C * kd[n*DI + c];
    }
    unsigned short hi, lo; split_bf16(v, hi, lo);
    Bp[idx] = hi; Bp[BPELEMS + idx] = lo;
    return;
  }
  int id2 = idx - BPELEMS;
  if (id2 < BDELEMS){
    int q = id2 & 31; int n = (id2 >> 5) % NPAD; int ks = id2 / (NPAD*32);
    int k = ks*32 + q;
    int t = k / DI, c = k % DI;
    float v = 0.f;
    if (n < NKO){
      float kv = kd[n*DI + c];
      v = (t == 0) ? kv : -kv;
    }
    unsigned short hi, lo; split_bf16(v, hi, lo);
    Bd[id2] = hi; Bd[BDELEMS + id2] = lo;
    return;
  }
  int id3 = id2 - BDELEMS;
  if (id3 < AZTOT){
    int arr = id3 / (AZTOT/2); int r = id3 % (AZTOT/2);
    int k8 = r % 96; r /= 96;
    int b = r / 228; int pi = r % 228;
    int row, col;
    if (pi < 58){ row = 0; col = pi; }
    else if (pi < 116){ row = 57; col = pi - 58; }
    else if (pi < 172){ row = pi - 115; col = 0; }
    else { row = pi - 171; col = 57; }
    unsigned short* p = (arr ? Al : Ah) + ((size_t)b*PIXP + (size_t)row*HP + col)*KK + k8*4;
    *(unsigned long long*)p = 0ULL;
    return;
  }
  int id4 = id3 - AZTOT;
  if (id4 < TOPWN){
    int d = id4 / DI, dd = id4 % DI;
    opwT[dd*96 + d] = opw[id4];
  }
}

// ---------------- K5c: pack A ----------------
__global__ __launch_bounds__(256) void k_apack(const float* __restrict__ xc,
                                               const float* __restrict__ xtc,
                                               unsigned short* __restrict__ Ah,
                                               unsigned short* __restrict__ Al){
  __shared__ float tile[64*57];
  int h = blockIdx.x, b = blockIdx.y, z = blockIdx.z;
  int t = z / 3, cc = z % 3;
  const float* src = (t ? xtc : xc) + (size_t)b*DI*LL;
  for (int i = threadIdx.x; i < 64*56; i += 256){
    int ci = i / 56, wpx = i % 56;
    tile[ci*57 + wpx] = src[(size_t)(cc*64 + ci)*LL + h*WW + wpx];
  }
  __syncthreads();
  int cl = threadIdx.x & 63, wv = threadIdx.x >> 6;
  for (int wp = wv; wp < WW; wp += 4){
    float v = tile[cl*57 + wp];
    unsigned short hi, lo; split_bf16(v, hi, lo);
    size_t eo = ((size_t)b*PIXP + (size_t)(h+1)*HP + (wp+1))*KK + t*DI + cc*64 + cl;
    Ah[eo] = hi; Al[eo] = lo;
  }
}

// ---------------- K5d: MFMA GEMM v5 — 4-wave blocks, B staged in LDS ----------------
__global__ __launch_bounds__(256) void k_gemm(const unsigned short* __restrict__ Ah,
                                              const unsigned short* __restrict__ Al,
                                              const unsigned short* __restrict__ Bp,
                                              const unsigned short* __restrict__ Bd,
                                              float* __restrict__ parts){
  __shared__ short Bs[60*512];
  int tid = threadIdx.x;
  int lane = tid & 63, wave = tid >> 6;
  int cl = lane & 15, kg = lane >> 4;
  int mg = blockIdx.x;
  int y = blockIdx.y;
  bool isDiff = (y >= 6);
  int ch = y & 1;
  int og = y >> 1;
  int col = ch*80 + cl;

  size_t aoff[2];
  #pragma unroll
  for (int mi = 0; mi < 2; ++mi){
    int p = mg*128 + (wave*2 + mi)*16 + cl;
    int b = p / LL, l = p % LL;
    int h = l / WW, wp = l % WW;
    aoff[mi] = ((size_t)b*PIXP + (size_t)h*HP + wp)*KK + kg*8;
  }

  f4v acc[2][5];
  #pragma unroll
  for (int mi = 0; mi < 2; ++mi)
    #pragma unroll
    for (int nf = 0; nf < 5; ++nf) acc[mi][nf] = (f4v){0.f,0.f,0.f,0.f};

  const int nStages = isDiff ? 2 : 6;
  for (int st = 0; st < nStages; ++st){
    int oo = st >> 1;
    int kh = st & 1;
    int off = 3*og + oo;
    int ksBase = isDiff ? st*6 : (off*12 + kh*6);
    const unsigned short* Bh = isDiff ? Bd : Bp;
    size_t loSkip = isDiff ? (size_t)BDELEMS : (size_t)BPELEMS;

    __syncthreads();
    #pragma unroll
    for (int i = 0; i < 15; ++i){
      int slot = tid + 256*i;
      int fi = slot >> 6, lv = slot & 63;
      int cl2 = lv & 15, kg2 = lv >> 4;
      int ksl = fi / 10, r = fi % 10;
      int hl = r / 5, nf = r % 5;
      size_t gs = ((size_t)(ksBase + ksl)*NPAD + ch*80 + nf*16 + cl2)*32 + kg2*8
                + (hl ? loSkip : 0);
      *(s8v*)(Bs + fi*512 + lv*8) = *(const s8v*)(Bh + gs);
    }
    __syncthreads();

    size_t ashift = isDiff ? (size_t)(HP + 1)*KK
                           : (size_t)((off/3)*HP + (off%3))*KK;
    int ks0 = isDiff ? st*6 : kh*6;
    #pragma unroll 2
    for (int ksl = 0; ksl < 6; ++ksl){
      s8v bh[5], bl[5];
      #pragma unroll
      for (int nf = 0; nf < 5; ++nf){
        bh[nf] = *(const s8v*)(Bs + (ksl*10 + nf)*512 + lane*8);
        bl[nf] = *(const s8v*)(Bs + (ksl*10 + 5 + nf)*512 + lane*8);
      }
      #pragma unroll
      for (int mi = 0; mi < 2; ++mi){
        size_t ao = aoff[mi] + ashift + (size_t)(ks0 + ksl)*32;
        s8v ahv = *(const s8v*)(Ah + ao);
        s8v alv = *(const s8v*)(Al + ao);
        #pragma unroll
        for (int nf = 0; nf < 5; ++nf)
          acc[mi][nf] = __builtin_amdgcn_mfma_f32_16x16x32_bf16(ahv, bh[nf], acc[mi][nf], 0, 0, 0);
        #pragma unroll
        for (int nf = 0; nf < 5; ++nf)
          acc[mi][nf] = __builtin_amdgcn_mfma_f32_16x16x32_bf16(alv, bh[nf], acc[mi][nf], 0, 0, 0);
        #pragma unroll
        for (int nf = 0; nf < 5; ++nf)
          acc[mi][nf] = __builtin_amdgcn_mfma_f32_16x16x32_bf16(ahv, bl[nf], acc[mi][nf], 0, 0, 0);
      }
    }
  }

  int q = isDiff ? 3 : og;
  float* part = parts + (size_t)q*PSZ;
  #pragma unroll
  for (int mi = 0; mi < 2; ++mi){
    int prow0 = mg*128 + (wave*2 + mi)*16 + kg*4;
    #pragma unroll
    for (int nf = 0; nf < 5; ++nf){
      int c2 = col + nf*16;
      #pragma unroll
      for (int i = 0; i < 4; ++i)
        part[(size_t)(prow0 + i)*NPAD + c2] = acc[mi][nf][i];
    }
  }
}

// ---------------- K5e: combine partials -> pooled ----------------
__global__ __launch_bounds__(256) void k_pool(const float* __restrict__ parts,
                                              float* __restrict__ pooled){
  int idx = blockIdx.x*256 + threadIdx.x;
  if (idx >= NB*LL*NKO) return;
  int ko = idx % NKO; int l = idx / NKO;
  size_t e = (size_t)l*NPAD + ko;
  float lin = parts[e] + parts[PSZ + e] + parts[2*PSZ + e];
  float dv = parts[3*PSZ + e];
  float pv = lin + 0.5f*THETA_C*fabsf(dv);
  int b = l / LL, ll = l % LL;
  int k = ko / NCOUT, o = ko % NCOUT;
  pooled[(((size_t)b*4 + k)*LL + ll)*NCOUT + o] = pv;
}

// ---------------- K6a: scan pass A ----------------
__global__ __launch_bounds__(64) void k_scanA(const float* __restrict__ pooled,
                                              const float* __restrict__ xs,
                                              const float* __restrict__ dtw,
                                              const float* __restrict__ dtb,
                                              const float* __restrict__ alog,
                                              float* __restrict__ Pb,
                                              float* __restrict__ He){
  int d = blockIdx.z*64 + threadIdx.x;
  int bk = blockIdx.y;
  int c = blockIdx.x;
  int k = bk & 3, b = bk >> 2;
  int kdix = k*DI + d;
  int dir = (k >> 1) & 1;
  int flip = k & 1;
  float A[NST], P[NST], hst[NST];
  #pragma unroll
  for (int n = 0; n < NST; ++n){ A[n] = -__expf(alog[kdix*NST + n]); P[n] = 1.f; hst[n] = 0.f; }
  float dwv[NDTR];
  #pragma unroll
  for (int r = 0; r < NDTR; ++r) dwv[r] = dtw[kdix*NDTR + r];
  float db = dtb[kdix];
  const float* prow = pooled + ((size_t)bk*LL + c*CLEN)*NCOUT;
  const float* xsd = xs + ((size_t)(b*2 + dir)*LL)*DI + d;
  int pos = c*CLEN;
  int wp = pos % 56, rowb = pos - wp;
  for (int p = 0; p < CLEN; ++p){
    float xr = db;
    #pragma unroll
    for (int r = 0; r < NDTR; ++r) xr += prow[r]*dwv[r];
    float delta = softplusf(xr);
    int upos = flip ? (rowb + 55 - wp) : pos;
    float u = xsd[(size_t)upos*DI];
    float du = delta * u;
    #pragma unroll
    for (int n = 0; n < NST; ++n){
      float dA = __expf(delta * A[n]);
      P[n]  *= dA;
      hst[n] = dA*hst[n] + du*prow[6+n];
    }
    prow += NCOUT;
    ++pos; ++wp; if (wp == 56){ wp = 0; rowb = pos; }
  }
  float* pp = Pb + (((size_t)bk*NCH + c)*DI + d)*NST;
  float* hp = He + (((size_t)bk*NCH + c)*DI + d)*NST;
  #pragma unroll
  for (int n = 0; n < NST; ++n){ pp[n] = P[n]; hp[n] = hst[n]; }
}

// ---------------- K6b: cross-chunk prefix -> H0 (separate buffer, R6-proven) ----------------
__global__ __launch_bounds__(256) void k_scanB(const float* __restrict__ Pb,
                                               const float* __restrict__ He,
                                               float* __restrict__ H0){
  int t = blockIdx.x*256 + threadIdx.x;
  if (t >= NB*4*DI*NST) return;
  int bk = t / (DI*NST);
  int dn = t % (DI*NST);
  float hcur = 0.f;
  for (int c = 0; c < NCH; ++c){
    size_t off = ((size_t)bk*NCH + c)*DI*NST + dn;
    H0[off] = hcur;
    hcur = Pb[off]*hcur + He[off];
  }
}

// ---------------- K6c: scan pass C ----------------
__global__ __launch_bounds__(64) void k_scanC(const float* __restrict__ pooled,
                                              const float* __restrict__ xs,
                                              const float* __restrict__ dtw,
                                              const float* __restrict__ dtb,
                                              const float* __restrict__ alog,
                                              const float* __restrict__ Dsv,
                                              const float* __restrict__ H0,
                                              float* __restrict__ oy){
  int d = blockIdx.z*64 + threadIdx.x;
  int bk = blockIdx.y;
  int c = blockIdx.x;
  int k = bk & 3, b = bk >> 2;
  int kdix = k*DI + d;
  int dir = (k >> 1) & 1;
  int flip = k & 1;
  float A[NST], hst[NST];
  const float* h0p = H0 + (((size_t)bk*NCH + c)*DI + d)*NST;
  #pragma unroll
  for (int n = 0; n < NST; ++n){ A[n] = -__expf(alog[kdix*NST + n]); hst[n] = h0p[n]; }
  float dwv[NDTR];
  #pragma unroll
  for (int r = 0; r < NDTR; ++r) dwv[r] = dtw[kdix*NDTR + r];
  float db = dtb[kdix];
  float Dv = Dsv[kdix];
  const float* prow = pooled + ((size_t)bk*LL + c*CLEN)*NCOUT;
  const float* xsd = xs + ((size_t)(b*2 + dir)*LL)*DI + d;
  float* orow = oy + ((size_t)bk*LL + c*CLEN)*DI + d;
  int pos = c*CLEN;
  int wp = pos % 56, rowb = pos - wp;
  for (int p = 0; p < CLEN; ++p){
    float xr = db;
    #pragma unroll
    for (int r = 0; r < NDTR; ++r) xr += prow[r]*dwv[r];
    float delta = softplusf(xr);
    int upos = flip ? (rowb + 55 - wp) : pos;
    float u = xsd[(size_t)upos*DI];
    float du = delta * u;
    float y = 0.f;
    #pragma unroll
    for (int n = 0; n < NST; ++n){
      float dA = __expf(delta * A[n]);
      hst[n] = dA*hst[n] + du*prow[6+n];
      y += hst[n]*prow[22+n];
    }
    orow[0] = y + Dv*u;
    prow += NCOUT; orow += DI;
    ++pos; ++wp; if (wp == 56){ wp = 0; rowb = pos; }
  }
}

// ---------------- K7: merge + LN + gate + out_proj (split dot) ----------------
__global__ __launch_bounds__(192) void k_out(const float* __restrict__ oy,
                                             const float* __restrict__ xz,
                                             const float* __restrict__ lng,
                                             const float* __restrict__ lnb,
                                             const float* __restrict__ opwT,
                                             float* __restrict__ out){
  __shared__ float ygs[DI];
  __shared__ float pacc[96];
  __shared__ float redS[3], redQ[3];
  int bl = blockIdx.x; int b = bl / LL; int l = bl % LL;
  int d = threadIdx.x;
  int h = l / WW, wp = l % WW;
  int p2 = wp*HH + h;
  size_t b4 = (size_t)b*4;
  float y = oy[((b4+0)*LL + l)*DI + d]
          + oy[((b4+2)*LL + (LL-1-l))*DI + d]
          + oy[((b4+1)*LL + p2)*DI + d]
          + oy[((b4+3)*LL + (LL-1-p2))*DI + d];
  float s = y, q = y*y;
  #pragma unroll
  for (int m = 1; m < 64; m <<= 1){ s += __shfl_xor(s, m); q += __shfl_xor(q, m); }
  int wv = d >> 6;
  if ((d & 63) == 0){ redS[wv] = s; redQ[wv] = q; }
  __syncthreads();
  float S = redS[0]+redS[1]+redS[2];
  float Q = redQ[0]+redQ[1]+redQ[2];
  float mu = S * (1.f/DI);
  float var = Q * (1.f/DI) - mu*mu;
  float yn = (y - mu) * rsqrtf(var + 1e-5f) * lng[d] + lnb[d];
  float zv = xz[((size_t)b*384 + 192 + d)*LL + l];
  ygs[d] = yn * siluf(zv);
  __syncthreads();
  int half = d / 96, dc = d - half*96;
  float acc = 0.f;
  int dd0 = half * 96;
  #pragma unroll 8
  for (int dd = dd0; dd < dd0 + 96; ++dd) acc += ygs[dd] * opwT[dd*96 + dc];
  if (half) pacc[dc] = acc;
  __syncthreads();
  if (!half) out[(size_t)bl*96 + dc] = acc + pacc[dc];
}

extern "C" void kernel_launch(void* const* d_in, const int* in_sizes, int n_in,
                              void* d_out, int out_size, void* d_ws, size_t ws_size,
                              hipStream_t stream){
  const float* x    = (const float*)d_in[0];
  const float* xt   = (const float*)d_in[1];
  const float* ipw  = (const float*)d_in[2];
  const float* c2w  = (const float*)d_in[3];
  const float* c2b  = (const float*)d_in[4];
  const float* cxw  = (const float*)d_in[5];
  const float* cxb  = (const float*)d_in[6];
  const float* xpw  = (const float*)d_in[7];
  const float* dtw  = (const float*)d_in[8];
  const float* dtb  = (const float*)d_in[9];
  const float* alog = (const float*)d_in[10];
  const float* Dsv  = (const float*)d_in[11];
  const float* lng  = (const float*)d_in[12];
  const float* lnb  = (const float*)d_in[13];
  const float* opw  = (const float*)d_in[14];
  float* out = (float*)d_out;

  float* ws   = (float*)d_ws;
  float* xz   = ws;
  float* xc   = xz  + (size_t)NB*384*LL;
  float* xtc  = xc  + (size_t)NB*DI*LL;
  float* xs   = xtc + (size_t)NB*DI*LL;
  float* pool = xs  + (size_t)NB*2*LL*DI;
  float* kd   = pool+ (size_t)NB*4*LL*NCOUT;
  float* opwT = kd  + (size_t)NKO*DI;
  // U1: {Ah,Al,Bp,Bd packs} (conv3d stage) then {Pb, He, H0} (scan stage) — R6-proven pattern
  float* U1   = opwT + (size_t)96*DI;          // 3*SCANSZ = 7,225,344 floats
  float* Pb   = U1;
  float* He   = Pb + SCANSZ;
  float* H0   = He + SCANSZ;
  unsigned short* Ahi = (unsigned short*)U1;
  unsigned short* Alo = Ahi + AELEMS;
  unsigned short* Bp  = Alo + AELEMS;
  unsigned short* Bd  = Bp + 2*BPELEMS;
  // U2: {parts[4], xtT} (conv3d stage) then {oy} (scan stage) — R6-proven pattern
  float* U2   = U1 + 3*SCANSZ;
  float* parts = U2;
  float* oy    = U2;
  float* xtT   = U2 + 4*PSZ;

  k_inproj<<<NB*LL/16, 512, 0, stream>>>(x, ipw, xz);
  k_txt<<<dim3(LL/16, NB), 256, 0, stream>>>(xt, xtT);
  k_kd<<<(NKO*DI+255)/256, 256, 0, stream>>>(xpw, kd);
  k_wpack<<<(BPELEMS+BDELEMS+AZTOT+TOPWN+255)/256, 256, 0, stream>>>(xpw, kd, opw, Bp, Bd, Ahi, Alo, opwT);
  int n1 = NB*DI*LL;
  k_conv<<<(2*n1+255)/256, 256, 0, stream>>>(xz, xtT, c2w, c2b, cxw, cxb, xc, xtc);
  k_xs<<<dim3(HH, NB, 6), 256, 0, stream>>>(xc, xtc, xs);
  k_apack<<<dim3(HH, NB, 6), 256, 0, stream>>>(xc, xtc, Ahi, Alo);
  k_gemm<<<dim3(49, 8), 256, 0, stream>>>(Ahi, Alo, Bp, Bd, parts);
  k_pool<<<(NB*LL*NKO+255)/256, 256, 0, stream>>>(parts, pool);
  k_scanA<<<dim3(NCH, NB*4, 3), 64, 0, stream>>>(pool, xs, dtw, dtb, alog, Pb, He);
  k_scanB<<<(NB*4*DI*NST+255)/256, 256, 0, stream>>>(Pb, He, H0);
  k_scanC<<<dim3(NCH, NB*4, 3), 64, 0, stream>>>(pool, xs, dtw, dtb, alog, Dsv, H0, oy);
  k_out<<<NB*LL, 192, 0, stream>>>(oy, xz, lng, lnb, opwT, out);
}